// Round 2
// baseline (179.269 us; speedup 1.0000x reference)
//
#include <hip/hip_runtime.h>

typedef _Float16 f16;
typedef __attribute__((ext_vector_type(4))) _Float16 f16x4;
typedef __attribute__((ext_vector_type(8))) _Float16 f16x8;
typedef __attribute__((ext_vector_type(4))) float f32x4;

#define MFMA32(a, b, c) __builtin_amdgcn_mfma_f32_16x16x32_f16((a), (b), (c), 0, 0, 0)

#if defined(__has_builtin)
#if __has_builtin(__builtin_amdgcn_mfma_f32_16x16x16f16)
#define HAVE_K16 1
#endif
#endif

#ifdef HAVE_K16
#define QK_ST 20   // 16 d-slots + 4 pad (40B row stride -> conflict-free b64 reads)
#else
#define QK_ST 36   // 32 k-slots (upper 16 zeroed) + 4 pad
#endif

// LDS map (bytes):
//   [XW_OFF, +9216)  : xw[64 tok][72 ch] f16 ; after B2 aliased by v[64 ch][72 tok]
//   [QT_OFF, +QSZ)   : q_t[4 head][64 tok][QK_ST] ; after B2c aliased by o_t[64 tok][72 ch]
//   [KT_OFF, +QSZ)   : k_t[4 head][64 tok][QK_ST]
//   [P_OFF,  +32768) : P[4 head][64 i][64 j] f16, 8-elem chunks XOR-swizzled by (i&7)
#define XW_OFF 0
#define QT_OFF 9216
#define QSZ    (4 * 64 * QK_ST * 2)
#define KT_OFF (QT_OFF + QSZ)
#define OT_OFF QT_OFF
#define P_OFF  (QT_OFF + 2 * QSZ)
#define SMEM_SZ (P_OFF + 4 * 64 * 64 * 2)

// One window (64 ch x 64 tok) per block; 4 waves; wave w == head w end-to-end.
__global__ __launch_bounds__(256, 2)
void wsa3d(const float* __restrict__ x,
           const float* __restrict__ Wq, const float* __restrict__ bq,
           const float* __restrict__ Wk, const float* __restrict__ bk,
           const float* __restrict__ Wv, const float* __restrict__ bv,
           const float* __restrict__ Wp, const float* __restrict__ bp,
           float* __restrict__ out)
{
    __shared__ __align__(16) unsigned char smem[SMEM_SZ];
    f16* const xw  = (f16*)(smem + XW_OFF);
    f16* const q_t = (f16*)(smem + QT_OFF);
    f16* const k_t = (f16*)(smem + KT_OFF);
    f16* const o_t = (f16*)(smem + OT_OFF);   // alias of q_t region (after B2c)
    f16* const Pl  = (f16*)(smem + P_OFF);
    f16* const vv  = (f16*)(smem + XW_OFF);   // alias of xw region (after B2)

    const int tid  = threadIdx.x;
    const int lane = tid & 63;
    const int w    = tid >> 6;      // wave id == head id
    const int g    = lane >> 4;     // MFMA k-group
    const int ln16 = lane & 15;

    // XCD-aware swizzle: consecutive bids round-robin XCDs; each XCD gets a
    // contiguous 1024-window slab (consecutive iw -> shared 64B lines in L2).
    const int bid = blockIdx.x;
    const int win = ((bid & 7) << 10) | (bid >> 3);
    const int iw = win & 15, ih = (win >> 4) & 15, idz = (win >> 8) & 15, b = win >> 12;

    // ---- weights (A-operand row w*16+ln16, k = 8g+ii+32s) + biases in registers
    const float* Wm[4]  = {Wq, Wk, Wv, Wp};
    const float* bmv[4] = {bq, bk, bv, bp};
    f16x8 wf[4][2];
    float bias[4][4];
    #pragma unroll
    for (int m = 0; m < 4; ++m) {
        #pragma unroll
        for (int s = 0; s < 2; ++s) {
            const float* src = Wm[m] + (w * 16 + ln16) * 64 + 8 * g + 32 * s;
            f32x4 a4 = *(const f32x4*)(src);
            f32x4 b4 = *(const f32x4*)(src + 4);
            #pragma unroll
            for (int ii = 0; ii < 8; ++ii)
                wf[m][s][ii] = (f16)(ii < 4 ? a4[ii] : b4[ii - 4]);
        }
        f32x4 bb = *(const f32x4*)(bmv[m] + w * 16 + g * 4);
        #pragma unroll
        for (int r = 0; r < 4; ++r) bias[m][r] = bb[r];
    }

    // ---- Phase A: gather x window -> xw[tok][72]
    {
        const int c = lane;
        const int lz = w;
        #pragma unroll
        for (int p = 0; p < 4; ++p) {
            const float* src = x + ((((b * 64 + c) * 64 + idz * 4 + lz) * 64) + ih * 4 + p) * 64 + iw * 4;
            f32x4 v4 = *(const f32x4*)src;
            #pragma unroll
            for (int lx = 0; lx < 4; ++lx)
                xw[(lz * 16 + p * 4 + lx) * 72 + c] = (f16)v4[lx];
        }
    }
    __syncthreads();   // B1: xw ready (cross-wave)

    // ---- projections q,k,v: wave w computes channel rows [16w,16w+16)
    f32x4 acc[3][4];
    #pragma unroll
    for (int m = 0; m < 3; ++m) {
        #pragma unroll
        for (int lb = 0; lb < 4; ++lb) {
            f32x4 a = {0.f, 0.f, 0.f, 0.f};
            #pragma unroll
            for (int s = 0; s < 2; ++s) {
                f16x8 xf = *(const f16x8*)(xw + (lb * 16 + ln16) * 72 + 8 * g + 32 * s);
                a = MFMA32(wf[m][s], xf, a);
            }
            acc[m][lb] = a;
        }
    }
    __syncthreads();   // B2: all xw reads done -> region reusable for v

    // ---- epilogue: bias + store q,k (per-head!), v (channel x token)
    #pragma unroll
    for (int lb = 0; lb < 4; ++lb) {
        const int tok = lb * 16 + ln16;
        #pragma unroll
        for (int r = 0; r < 4; ++r) {
            const int d = g * 4 + r;
            const int qbase = w * 64 * QK_ST + tok * QK_ST;
            q_t[qbase + d] = (f16)(acc[0][lb][r] + bias[0][r]);
            k_t[qbase + d] = (f16)(acc[1][lb][r] + bias[1][r]);
#ifndef HAVE_K16
            q_t[qbase + 16 + d] = (f16)0.f;   // zero upper k-half for K=32 fallback
            k_t[qbase + 16 + d] = (f16)0.f;
#endif
            vv[(w * 16 + d) * 72 + tok] = (f16)(acc[2][lb][r] + bias[2][r]);
        }
    }
    // q/k/v/P are intra-wave from here (wave w wrote and reads only head w).

    // ---- QK^T fragment loads (must finish before o_t aliases this region)
#ifdef HAVE_K16
    f16x4 qa[4], kb[4];
    #pragma unroll
    for (int ib = 0; ib < 4; ++ib)
        qa[ib] = *(const f16x4*)(q_t + w * 64 * QK_ST + (ib * 16 + ln16) * QK_ST + 4 * g);
    #pragma unroll
    for (int jb = 0; jb < 4; ++jb)
        kb[jb] = *(const f16x4*)(k_t + w * 64 * QK_ST + (jb * 16 + ln16) * QK_ST + 4 * g);
#else
    f16x8 qa[4], kb[4];
    #pragma unroll
    for (int ib = 0; ib < 4; ++ib) {
        const f16* p0 = q_t + w * 64 * QK_ST + (ib * 16 + ln16) * QK_ST + 8 * g;
        f16x4 lo = *(const f16x4*)(p0), hi = *(const f16x4*)(p0 + 4);
        #pragma unroll
        for (int ii = 0; ii < 4; ++ii) { qa[ib][ii] = lo[ii]; qa[ib][4 + ii] = hi[ii]; }
    }
    #pragma unroll
    for (int jb = 0; jb < 4; ++jb) {
        const f16* p0 = k_t + w * 64 * QK_ST + (jb * 16 + ln16) * QK_ST + 8 * g;
        f16x4 lo = *(const f16x4*)(p0), hi = *(const f16x4*)(p0 + 4);
        #pragma unroll
        for (int ii = 0; ii < 4; ++ii) { kb[jb][ii] = lo[ii]; kb[jb][4 + ii] = hi[ii]; }
    }
#endif
    __syncthreads();   // B2c: all q/k reads done (all waves) -> region reusable for o_t

    const f32x4 z4 = {0.f, 0.f, 0.f, 0.f};
    f32x4 S[4][4];
    #pragma unroll
    for (int jb = 0; jb < 4; ++jb) {
        #pragma unroll
        for (int ib = 0; ib < 4; ++ib) {
#ifdef HAVE_K16
            S[ib][jb] = __builtin_amdgcn_mfma_f32_16x16x16f16(qa[ib], kb[jb], z4, 0, 0, 0);
#else
            S[ib][jb] = MFMA32(qa[ib], kb[jb], z4);
#endif
        }
    }

    // ---- softmax over j (row i lives in 16 lanes sharing g; 4 j's per lane)
    const float c_sc = 0.25f * 1.44269504088896340736f;  // scale * log2(e)
    #pragma unroll
    for (int ib = 0; ib < 4; ++ib) {
        #pragma unroll
        for (int r = 0; r < 4; ++r) {
            float s0 = S[ib][0][r], s1 = S[ib][1][r], s2 = S[ib][2][r], s3 = S[ib][3][r];
            float mx = fmaxf(fmaxf(s0, s1), fmaxf(s2, s3));
            mx = fmaxf(mx, __shfl_xor(mx, 1));
            mx = fmaxf(mx, __shfl_xor(mx, 2));
            mx = fmaxf(mx, __shfl_xor(mx, 4));
            mx = fmaxf(mx, __shfl_xor(mx, 8));
            float e0 = exp2f((s0 - mx) * c_sc);
            float e1 = exp2f((s1 - mx) * c_sc);
            float e2 = exp2f((s2 - mx) * c_sc);
            float e3 = exp2f((s3 - mx) * c_sc);
            float sum = e0 + e1 + e2 + e3;
            sum += __shfl_xor(sum, 1);
            sum += __shfl_xor(sum, 2);
            sum += __shfl_xor(sum, 4);
            sum += __shfl_xor(sum, 8);
            const float inv = 1.0f / sum;
            const int i = ib * 16 + g * 4 + r;
            f16* prow = Pl + w * 4096 + i * 64;
            const int sub = ln16 >> 3, jcol = ln16 & 7, sw = i & 7;
            prow[(((0 + sub) ^ sw) * 8) + jcol] = (f16)(e0 * inv);
            prow[(((2 + sub) ^ sw) * 8) + jcol] = (f16)(e1 * inv);
            prow[(((4 + sub) ^ sw) * 8) + jcol] = (f16)(e2 * inv);
            prow[(((6 + sub) ^ sw) * 8) + jcol] = (f16)(e3 * inv);
        }
    }

    // ---- PV: out[d][i] = sum_j v[d][j] * P[i][j]
    f32x4 O[4];
    #pragma unroll
    for (int nb = 0; nb < 4; ++nb) O[nb] = z4;
    #pragma unroll
    for (int s = 0; s < 2; ++s) {
        f16x8 va = *(const f16x8*)(vv + (w * 16 + ln16) * 72 + 8 * g + 32 * s);
        #pragma unroll
        for (int nb = 0; nb < 4; ++nb) {
            const int i = nb * 16 + ln16;
            f16x8 pb = *(const f16x8*)(Pl + w * 4096 + i * 64 + (((g + 4 * s) ^ (i & 7)) * 8));
            O[nb] = MFMA32(va, pb, O[nb]);
        }
    }

    // ---- PV epilogue -> o_t[tok][72 ch] (aliases q/k region; safe after B2c)
    #pragma unroll
    for (int nb = 0; nb < 4; ++nb) {
        const int tok = nb * 16 + ln16;
        #pragma unroll
        for (int r = 0; r < 4; ++r)
            o_t[tok * 72 + (w * 16 + g * 4 + r)] = (f16)O[nb][r];
    }
    __syncthreads();   // B3: all heads' columns of o_t ready (cross-wave)

    // ---- output projection + scatter
    #pragma unroll
    for (int lb = 0; lb < 4; ++lb) {
        f32x4 a = z4;
        #pragma unroll
        for (int s = 0; s < 2; ++s) {
            f16x8 of = *(const f16x8*)(o_t + (lb * 16 + ln16) * 72 + 8 * g + 32 * s);
            a = MFMA32(wf[3][s], of, a);
        }
        const int ly = ln16 >> 2, lx = ln16 & 3;   // token l = lb*16+ln16 -> lz=lb
        #pragma unroll
        for (int r = 0; r < 4; ++r) {
            const int o = w * 16 + g * 4 + r;
            out[((((b * 64 + o) * 64 + idz * 4 + lb) * 64) + ih * 4 + ly) * 64 + iw * 4 + lx]
                = a[r] + bias[3][r];
        }
    }
}

extern "C" void kernel_launch(void* const* d_in, const int* in_sizes, int n_in,
                              void* d_out, int out_size, void* d_ws, size_t ws_size,
                              hipStream_t stream) {
    (void)in_sizes; (void)n_in; (void)out_size; (void)d_ws; (void)ws_size;
    const float* x  = (const float*)d_in[0];
    const float* Wq = (const float*)d_in[1];
    const float* bq = (const float*)d_in[2];
    const float* Wk = (const float*)d_in[3];
    const float* bk = (const float*)d_in[4];
    const float* Wv = (const float*)d_in[5];
    const float* bv = (const float*)d_in[6];
    const float* Wp = (const float*)d_in[7];
    const float* bp = (const float*)d_in[8];
    wsa3d<<<8192, 256, 0, stream>>>(x, Wq, bq, Wk, bk, Wv, bv, Wp, bp, (float*)d_out);
}

// Round 4
// 164.454 us; speedup vs baseline: 1.0901x; 1.0901x over previous
//
#include <hip/hip_runtime.h>

typedef _Float16 f16;
typedef __attribute__((ext_vector_type(4))) _Float16 f16x4;
typedef __attribute__((ext_vector_type(8))) _Float16 f16x8;
typedef __attribute__((ext_vector_type(4))) float f32x4;

#define MFMA32(a, b, c) __builtin_amdgcn_mfma_f32_16x16x32_f16((a), (b), (c), 0, 0, 0)
#define MFMA16(a, b, c) __builtin_amdgcn_mfma_f32_16x16x16f16((a), (b), (c), 0, 0, 0)

// LDS (f16 halves), 40,960 B total = exactly 4 blocks/CU:
//   lds[0..4096)      : xw[64 tok][64 ch]   (gather)  -- swizzled: elem(r,c) at r*64 + (c ^ ((r&7)<<3))
//                       aliased by vv[64 ch][64 tok] after B2, by o_t[64 tok][64 ch] after B_pv
//   lds[4096..20480)  : Pt[4 head][64 i][64 j]  P^T rows, same swizzle
// All b128 reads / b64 stores are chunk-XOR swizzled -> ~2-way bank conflicts max.
__global__ __launch_bounds__(256, 4)
void wsa3d(const float* __restrict__ x,
           const float* __restrict__ Wq, const float* __restrict__ bq,
           const float* __restrict__ Wk, const float* __restrict__ bk,
           const float* __restrict__ Wv, const float* __restrict__ bv,
           const float* __restrict__ Wp, const float* __restrict__ bp,
           float* __restrict__ out)
{
    __shared__ __align__(16) f16 lds[20480];
    f16* const xw = lds;           // gather buffer / vv / o_t (aliased, barrier-separated)
    f16* const Pt = lds + 4096;    // P^T per head

    const int tid  = threadIdx.x;
    const int lane = tid & 63;
    const int w    = tid >> 6;     // wave id == head id
    const int g    = lane >> 4;
    const int ln16 = lane & 15;
    const int key  = ln16 & 7;     // XOR-swizzle key for rows ending in ln16

    // XCD-aware swizzle: 1024-window contiguous slab per XCD
    const int bid = blockIdx.x;
    const int win = ((bid & 7) << 10) | (bid >> 3);
    const int iw = win & 15, ih = (win >> 4) & 15, idz = (win >> 8) & 15, b = win >> 12;

    const float c_sc = 0.25f * 1.44269504088896340736f;  // scale * log2(e), folded into q
    const f32x4 z4 = {0.f, 0.f, 0.f, 0.f};

    // ---- weight fragments Wq/Wk/Wv (A-operand: row = w*16+ln16, k = 8g+ii+32s) + biases
    f16x8 wfa[3][2];
    f32x4 bqv, bkv, bvv;
    {
        const float* Wm[3] = {Wq, Wk, Wv};
        #pragma unroll
        for (int m = 0; m < 3; ++m)
            #pragma unroll
            for (int s = 0; s < 2; ++s) {
                const float* src = Wm[m] + (w * 16 + ln16) * 64 + 8 * g + 32 * s;
                f32x4 a4 = *(const f32x4*)src;
                f32x4 b4 = *(const f32x4*)(src + 4);
                #pragma unroll
                for (int ii = 0; ii < 8; ++ii)
                    wfa[m][s][ii] = (f16)(ii < 4 ? a4[ii] : b4[ii - 4]);
            }
        bqv = *(const f32x4*)(bq + w * 16 + g * 4);
        bkv = *(const f32x4*)(bk + w * 16 + g * 4);
        bvv = *(const f32x4*)(bv + w * 16 + g * 4);
    }

    // ---- Phase A: gather x window -> xw[tok][ch] (swizzled)
    {
        const int c = lane;           // channel; wave w covers depth-row lz = w
        #pragma unroll
        for (int p = 0; p < 4; ++p) {
            const float* src = x + ((((b * 64 + c) * 64 + idz * 4 + w) * 64) + ih * 4 + p) * 64 + iw * 4;
            f32x4 v4 = *(const f32x4*)src;
            #pragma unroll
            for (int lx = 0; lx < 4; ++lx) {
                const int l = w * 16 + p * 4 + lx;
                xw[l * 64 + (c ^ ((l & 7) << 3))] = (f16)v4[lx];
            }
        }
    }
    __syncthreads();   // B1: xw ready

    // ---- projections q,k,v (wave w -> channel rows [16w,16w+16) = head w)
    f32x4 accq[4], acck[4], accv[4];
    #pragma unroll
    for (int t = 0; t < 4; ++t) { accq[t] = z4; acck[t] = z4; accv[t] = z4; }
    #pragma unroll
    for (int lb = 0; lb < 4; ++lb)
        #pragma unroll
        for (int s = 0; s < 2; ++s) {
            f16x8 xf = *(const f16x8*)(xw + (lb * 16 + ln16) * 64 + (((g + 4 * s) ^ key) << 3));
            accq[lb] = MFMA32(wfa[0][s], xf, accq[lb]);
            acck[lb] = MFMA32(wfa[1][s], xf, acck[lb]);
            accv[lb] = MFMA32(wfa[2][s], xf, accv[lb]);
        }
    __syncthreads();   // B2: all xw reads done -> region becomes vv

    // ---- epilogue: q/k straight into K16 fragments (NO LDS round trip: proj C/D layout ==
    //      K16 A/B frag layout: lane holds d=4g+r at token 16t+ln16); v -> LDS ch-major
    f16x4 qa[4], kb[4];
    #pragma unroll
    for (int t = 0; t < 4; ++t) {
        #pragma unroll
        for (int r = 0; r < 4; ++r) {
            qa[t][r] = (f16)((accq[t][r] + bqv[r]) * c_sc);   // fold softmax scale into q
            kb[t][r] = (f16)(acck[t][r] + bkv[r]);
        }
        #pragma unroll
        for (int r = 0; r < 4; ++r) {
            const int row = w * 16 + g * 4 + r;     // absolute channel
            const int tok = t * 16 + ln16;
            xw[row * 64 + (tok ^ ((row & 7) << 3))] = (f16)(accv[t][r] + bvv[r]);
        }
    }

    // ---- swapped QK^T: S^T[j][i] = mfma16(A=k, B=q); lane holds j = 16jb+4g+r,
    //      i = 16ib+ln16. No max-subtraction (|S| <~ 1.5, exp2 safe). Sum in-lane + 2 shfls.
    float inv[4];
    #pragma unroll
    for (int ib = 0; ib < 4; ++ib) {
        f32x4 e[4];
        #pragma unroll
        for (int jb = 0; jb < 4; ++jb) {
            f32x4 S = MFMA16(kb[jb], qa[ib], z4);
            #pragma unroll
            for (int r = 0; r < 4; ++r) e[jb][r] = __builtin_amdgcn_exp2f(S[r]);
        }
        f32x4 s4 = e[0] + e[1] + e[2] + e[3];
        float h = (s4[0] + s4[1]) + (s4[2] + s4[3]);
        h += __shfl_xor(h, 16);
        h += __shfl_xor(h, 32);
        inv[ib] = __builtin_amdgcn_rcpf(h);
        // store P^T rows i-major: 4 j-contiguous halves per (ib,jb) -> b64 stores
        // (RNE casts: P all-positive, RTZ would bias the P/sum normalization coherently)
        f16* dst = Pt + w * 4096 + (16 * ib + ln16) * 64;
        #pragma unroll
        for (int jb = 0; jb < 4; ++jb) {
            f16x4 pv;
            #pragma unroll
            for (int r = 0; r < 4; ++r) pv[r] = (f16)e[jb][r];
            *(f16x4*)(dst + ((((2 * jb + (g >> 1)) ^ key) << 3) + 4 * (g & 1))) = pv;
        }
    }

    // ---- PV: O[d][i] = sum_j v[d][j] * P^T[j][i]; A = vv rows (d = ln16), B = Pt rows
    f16x8 va[2];
    #pragma unroll
    for (int s = 0; s < 2; ++s)
        va[s] = *(const f16x8*)(xw + (w * 16 + ln16) * 64 + (((g + 4 * s) ^ key) << 3));
    f32x4 O[4];
    #pragma unroll
    for (int nb = 0; nb < 4; ++nb) O[nb] = z4;
    #pragma unroll
    for (int s = 0; s < 2; ++s)
        #pragma unroll
        for (int nb = 0; nb < 4; ++nb) {
            f16x8 pb = *(const f16x8*)(Pt + w * 4096 + (16 * nb + ln16) * 64 + (((g + 4 * s) ^ key) << 3));
            O[nb] = MFMA32(va[s], pb, O[nb]);
        }
    __syncthreads();   // B_pv: all vv reads done -> region becomes o_t

    // ---- normalize + o_t[tok][ch] (4 b64 stores; cols w16+4g..+3 contiguous pre-swizzle)
    #pragma unroll
    for (int nb = 0; nb < 4; ++nb) {
        const int tok = 16 * nb + ln16;
        f16x4 ov;
        #pragma unroll
        for (int r = 0; r < 4; ++r) ov[r] = (f16)(O[nb][r] * inv[nb]);
        *(f16x4*)(xw + tok * 64 + ((w * 16 + 4 * g) ^ (key << 3))) = ov;
    }
    __syncthreads();   // B3: o_t complete

    // ---- output projection, swapped: D2[t][o] = sum_c o_t[t][c] * Wp[o][c]
    //      A = o_t token-rows 16w..16w+15 (this wave's tokens), B = Wp rows (all 64 o).
    //      Lane holds t = 16w+4g+r (r = lx!), o = 16oc+ln16 -> coalesced f32x4 stores.
    f16x8 af[2];
    #pragma unroll
    for (int s = 0; s < 2; ++s)
        af[s] = *(const f16x8*)(xw + (w * 16 + ln16) * 64 + (((g + 4 * s) ^ key) << 3));
    #pragma unroll
    for (int oc = 0; oc < 4; ++oc) {
        f32x4 a = z4;
        #pragma unroll
        for (int s = 0; s < 2; ++s) {
            const float* src = Wp + (oc * 16 + ln16) * 64 + 8 * g + 32 * s;
            f32x4 a4 = *(const f32x4*)src;
            f32x4 b4 = *(const f32x4*)(src + 4);
            f16x8 wpf;
            #pragma unroll
            for (int ii = 0; ii < 8; ++ii)
                wpf[ii] = (f16)(ii < 4 ? a4[ii] : b4[ii - 4]);
            a = MFMA32(af[s], wpf, a);
        }
        const float bpo = bp[oc * 16 + ln16];
        f32x4 res = {a[0] + bpo, a[1] + bpo, a[2] + bpo, a[3] + bpo};
        // t = 16w + 4g + r -> lz = w, ly = g, lx = r (vectorized over x!)
        float* dst = out + ((((b * 64 + oc * 16 + ln16) * 64 + idz * 4 + w) * 64) + ih * 4 + g) * 64 + iw * 4;
        *(f32x4*)dst = res;
    }
}

extern "C" void kernel_launch(void* const* d_in, const int* in_sizes, int n_in,
                              void* d_out, int out_size, void* d_ws, size_t ws_size,
                              hipStream_t stream) {
    (void)in_sizes; (void)n_in; (void)out_size; (void)d_ws; (void)ws_size;
    const float* x  = (const float*)d_in[0];
    const float* Wq = (const float*)d_in[1];
    const float* bq = (const float*)d_in[2];
    const float* Wk = (const float*)d_in[3];
    const float* bk = (const float*)d_in[4];
    const float* Wv = (const float*)d_in[5];
    const float* bv = (const float*)d_in[6];
    const float* Wp = (const float*)d_in[7];
    const float* bp = (const float*)d_in[8];
    wsa3d<<<8192, 256, 0, stream>>>(x, Wq, bq, Wk, bk, Wv, bv, Wp, bp, (float*)d_out);
}

// Round 5
// 74.788 us; speedup vs baseline: 2.3970x; 2.1989x over previous
//
#include <hip/hip_runtime.h>

typedef _Float16 f16;
typedef __attribute__((ext_vector_type(4))) _Float16 f16x4;
typedef __attribute__((ext_vector_type(8))) _Float16 f16x8;
typedef __attribute__((ext_vector_type(4))) float f32x4;

#define MFMA32(a,b,c) __builtin_amdgcn_mfma_f32_16x16x32_f16((a),(b),(c),0,0,0)
#define MFMA16(a,b,c) __builtin_amdgcn_mfma_f32_16x16x16f16((a),(b),(c),0,0,0)

// One block = 4 consecutive-iw windows ("quad"); wave w owns window w end-to-end.
// LDS 64KB:
//   XW [0,32KB):  per-window 8KB: xw[64t][64c] -> vv[64c][64t] -> o_t[64t][64c] (aliased, ordered)
//   PT [32,64KB): Wqkv f16 staging (24KB, dies at B2) -> per-window P[64i][64j] (4x8KB)
//                 -> Wp f16 (8KB) + f32 out-staging (17.5KB)
// All tiles chunk-XOR swizzled: elem(row,col) at row*64 + (col8 ^ (row&7) ^ qw)*8 + col&7.
__global__ __launch_bounds__(256, 2)
void wsa3d(const float* __restrict__ x,
           const float* __restrict__ Wq, const float* __restrict__ bq,
           const float* __restrict__ Wk, const float* __restrict__ bk,
           const float* __restrict__ Wv, const float* __restrict__ bv,
           const float* __restrict__ Wp, const float* __restrict__ bp,
           float* __restrict__ out)
{
    __shared__ __align__(16) f16 lds[32768];
    f16* const XW = lds;
    f16* const PT = lds + 16384;

    const int tid  = threadIdx.x;
    const int lane = tid & 63;
    const int w    = tid >> 6;     // wave id == window-in-quad
    const int g    = lane >> 4;
    const int ln16 = lane & 15;
    const int key  = ln16 & 7;

    // XCD swizzle (2048 % 8 == 0 -> bijective): 256 consecutive quads per XCD
    const int bid = blockIdx.x;
    const int Q   = ((bid & 7) << 8) | (bid >> 3);
    const int qx = Q & 3, ih = (Q >> 2) & 15, idz = (Q >> 6) & 15, b = Q >> 10;

    const float c_sc = 0.25f * 1.44269504088896340736f;  // scale * log2(e)
    const f32x4 z4 = {0.f, 0.f, 0.f, 0.f};

    // gather/store lane roles: window gq, spatial (gz,gy)
    const int gz = (lane >> 4) & 3, gy = (lane >> 2) & 3, gq = lane & 3;

    // ---- Phase G: coalesced gather. inst i -> channel c = w*16+i; 16 lines/inst.
    f32x4 vals[16];
    #pragma unroll
    for (int i = 0; i < 16; ++i) {
        const int c = w * 16 + i;
        vals[i] = *(const f32x4*)(x + ((((b*64 + c)*64 + idz*4 + gz)*64) + ih*4 + gy)*64 + qx*16 + gq*4);
    }

    // ---- Phase W: stage Wq/Wk/Wv -> PT as f16 (coalesced reads, swizzled b64 writes)
    {
        const float* Wm[3] = {Wq, Wk, Wv};
        #pragma unroll
        for (int j = 0; j < 12; ++j) {
            const int m   = j >> 2;
            const int row = (j & 3) * 16 + (tid >> 4);
            const int c0  = (tid & 15) * 4;
            f32x4 wv = *(const f32x4*)(Wm[m] + row * 64 + c0);
            f16x4 h4;
            #pragma unroll
            for (int r = 0; r < 4; ++r) h4[r] = (f16)wv[r];
            *(f16x4*)(PT + m*4096 + row*64 + (((c0 >> 3) ^ (row & 7)) << 3) + (c0 & 7)) = h4;
        }
    }

    // ---- gather pack -> xw[t][c] of window gq (token-major, swizzled)
    #pragma unroll
    for (int lx = 0; lx < 4; ++lx) {
        const int t = gz * 16 + gy * 4 + lx;
        #pragma unroll
        for (int h2 = 0; h2 < 2; ++h2) {
            f16x8 pk;
            #pragma unroll
            for (int ii = 0; ii < 8; ++ii) pk[ii] = (f16)vals[h2 * 8 + ii][lx];
            *(f16x8*)(XW + gq*4096 + t*64 + (((w*2 + h2) ^ (t & 7) ^ gq) << 3)) = pk;
        }
    }
    __syncthreads();   // B1: xw + W-LDS ready

    // ---- biases
    f32x4 bqv[4], bkv[4];
    float bvs[4];
    #pragma unroll
    for (int ob = 0; ob < 4; ++ob) {
        bqv[ob] = *(const f32x4*)(bq + ob * 16 + g * 4);
        bkv[ob] = *(const f32x4*)(bk + ob * 16 + g * 4);
        bvs[ob] = bv[ob * 16 + ln16];
    }

    // ---- xw fragments (serve as B for q/k and as A for v^T)
    f16x8 xf[4][2];
    #pragma unroll
    for (int lb = 0; lb < 4; ++lb)
        #pragma unroll
        for (int s = 0; s < 2; ++s)
            xf[lb][s] = *(const f16x8*)(XW + w*4096 + (lb*16 + ln16)*64 + (((g + 4*s) ^ key ^ w) << 3));

    // ---- q,k projections: C-layout == K16 fragment layout (lane: d=4g+r, tok=ln16)
    f16x4 qf[4][4], kf[4][4];
    #pragma unroll
    for (int mi = 0; mi < 2; ++mi) {
        #pragma unroll
        for (int ob = 0; ob < 4; ++ob) {
            f16x8 AF[2];
            #pragma unroll
            for (int s = 0; s < 2; ++s)
                AF[s] = *(const f16x8*)(PT + mi*4096 + (ob*16 + ln16)*64 + (((g + 4*s) ^ key) << 3));
            #pragma unroll
            for (int lb = 0; lb < 4; ++lb) {
                f32x4 a = z4;
                #pragma unroll
                for (int s = 0; s < 2; ++s) a = MFMA32(AF[s], xf[lb][s], a);
                f16x4 dst;
                if (mi == 0) {
                    #pragma unroll
                    for (int r = 0; r < 4; ++r) dst[r] = (f16)((a[r] + bqv[ob][r]) * c_sc);
                    qf[ob][lb] = dst;
                } else {
                    #pragma unroll
                    for (int r = 0; r < 4; ++r) dst[r] = (f16)(a[r] + bkv[ob][r]);
                    kf[ob][lb] = dst;
                }
            }
        }
    }

    // ---- v^T projection (A=xw, B=Wv-frags): lane holds t-run -> b64 channel-major stores
    #pragma unroll
    for (int ob = 0; ob < 4; ++ob) {
        f16x8 VF[2];
        #pragma unroll
        for (int s = 0; s < 2; ++s)
            VF[s] = *(const f16x8*)(PT + 2*4096 + (ob*16 + ln16)*64 + (((g + 4*s) ^ key) << 3));
        #pragma unroll
        for (int tb = 0; tb < 4; ++tb) {
            f32x4 a = z4;
            #pragma unroll
            for (int s = 0; s < 2; ++s) a = MFMA32(xf[tb][s], VF[s], a);
            f16x4 h4;
            #pragma unroll
            for (int r = 0; r < 4; ++r) h4[r] = (f16)(a[r] + bvs[ob]);
            *(f16x4*)(XW + w*4096 + (ob*16 + ln16)*64 + (((2*tb + (g >> 1)) ^ key ^ w) << 3) + 4*(g & 1)) = h4;
        }
    }
    __syncthreads();   // B2: all W-LDS reads done -> PT region becomes P buffers

    // ---- attention, head-sequential (all per-wave; DS same-wave ordering covers P/vv reuse)
    f16x4 ot[4][4];
    #pragma unroll
    for (int h = 0; h < 4; ++h) {
        float invv[4];
        #pragma unroll
        for (int ib = 0; ib < 4; ++ib) {
            f32x4 e[4];
            #pragma unroll
            for (int jb = 0; jb < 4; ++jb) {
                f32x4 S = MFMA16(kf[h][jb], qf[h][ib], z4);   // swapped: S^T[j][i]
                #pragma unroll
                for (int r = 0; r < 4; ++r) e[jb][r] = __builtin_amdgcn_exp2f(S[r]);
            }
            f32x4 s4 = e[0] + e[1] + e[2] + e[3];
            float hh = (s4[0] + s4[1]) + (s4[2] + s4[3]);
            hh += __shfl_xor(hh, 16);
            hh += __shfl_xor(hh, 32);
            invv[ib] = __builtin_amdgcn_rcpf(hh);
            f16* dst = PT + w*4096 + (ib*16 + ln16)*64;
            #pragma unroll
            for (int jb = 0; jb < 4; ++jb) {
                f16x4 pv;
                #pragma unroll
                for (int r = 0; r < 4; ++r) pv[r] = (f16)e[jb][r];
                *(f16x4*)(dst + (((2*jb + (g >> 1)) ^ key ^ w) << 3) + 4*(g & 1)) = pv;
            }
        }
        f16x8 va[2];
        #pragma unroll
        for (int s = 0; s < 2; ++s)
            va[s] = *(const f16x8*)(XW + w*4096 + (h*16 + ln16)*64 + (((g + 4*s) ^ key ^ w) << 3));
        f32x4 O[4] = {z4, z4, z4, z4};
        #pragma unroll
        for (int s = 0; s < 2; ++s)
            #pragma unroll
            for (int nb = 0; nb < 4; ++nb) {
                f16x8 pb = *(const f16x8*)(PT + w*4096 + (nb*16 + ln16)*64 + (((g + 4*s) ^ key ^ w) << 3));
                O[nb] = MFMA32(va[s], pb, O[nb]);
            }
        #pragma unroll
        for (int nb = 0; nb < 4; ++nb)
            #pragma unroll
            for (int r = 0; r < 4; ++r) ot[h][nb][r] = (f16)(O[nb][r] * invv[nb]);
    }

    // ---- o_t[t][c] into XW (vv dead, same-wave ordering)
    #pragma unroll
    for (int h = 0; h < 4; ++h)
        #pragma unroll
        for (int nb = 0; nb < 4; ++nb)
            *(f16x4*)(XW + w*4096 + (nb*16 + ln16)*64 + (((2*h + (g >> 1)) ^ key ^ w) << 3) + 4*(g & 1)) = ot[h][nb];
    __syncthreads();   // B_stg0: all P reads done -> PT becomes Wp + out-staging

    // ---- stage Wp (coalesced)
    #pragma unroll
    for (int j = 0; j < 4; ++j) {
        const int row = j * 16 + (tid >> 4);
        const int c0  = (tid & 15) * 4;
        f32x4 wv = *(const f32x4*)(Wp + row * 64 + c0);
        f16x4 h4;
        #pragma unroll
        for (int r = 0; r < 4; ++r) h4[r] = (f16)wv[r];
        *(f16x4*)(PT + row*64 + (((c0 >> 3) ^ (row & 7)) << 3) + (c0 & 7)) = h4;
    }
    __syncthreads();   // B_wp

    // ---- output projection: D2[t][o] = sum_c o_t[t][c] Wp[o][c]
    f16x8 wpf[4][2];
    #pragma unroll
    for (int oc = 0; oc < 4; ++oc)
        #pragma unroll
        for (int s = 0; s < 2; ++s)
            wpf[oc][s] = *(const f16x8*)(PT + (oc*16 + ln16)*64 + (((g + 4*s) ^ key) << 3));
    float bps[4];
    #pragma unroll
    for (int oc = 0; oc < 4; ++oc) bps[oc] = bp[oc * 16 + ln16];

    f32x4 res[4][4];
    #pragma unroll
    for (int tb = 0; tb < 4; ++tb) {
        f16x8 af[2];
        #pragma unroll
        for (int s = 0; s < 2; ++s)
            af[s] = *(const f16x8*)(XW + w*4096 + (tb*16 + ln16)*64 + (((g + 4*s) ^ key ^ w) << 3));
        #pragma unroll
        for (int oc = 0; oc < 4; ++oc) {
            f32x4 a = z4;
            #pragma unroll
            for (int s = 0; s < 2; ++s) a = MFMA32(af[s], wpf[oc][s], a);
            #pragma unroll
            for (int r = 0; r < 4; ++r) res[tb][oc][r] = a[r] + bps[oc];
        }
    }

    // ---- staged, coalesced output (4 rounds over oc)
    float* const SG = (float*)(PT + 4096);   // 4 windows x 1092 f32 (68-stride rows)
    #pragma unroll
    for (int oc = 0; oc < 4; ++oc) {
        #pragma unroll
        for (int tb = 0; tb < 4; ++tb)
            *(f32x4*)(SG + w*1092 + ln16*68 + ((tb*16 + g*4) ^ (w << 2))) = res[tb][oc];
        __syncthreads();
        #pragma unroll
        for (int si = 0; si < 4; ++si) {
            const int o2 = w * 4 + si;
            f32x4 v4 = *(const f32x4*)(SG + gq*1092 + o2*68 + ((gz*16 + gy*4) ^ (gq << 2)));
            *(f32x4*)(out + ((((b*64 + oc*16 + o2)*64 + idz*4 + gz)*64) + ih*4 + gy)*64 + qx*16 + gq*4) = v4;
        }
        if (oc < 3) __syncthreads();
    }
}

extern "C" void kernel_launch(void* const* d_in, const int* in_sizes, int n_in,
                              void* d_out, int out_size, void* d_ws, size_t ws_size,
                              hipStream_t stream) {
    (void)in_sizes; (void)n_in; (void)out_size; (void)d_ws; (void)ws_size;
    const float* x  = (const float*)d_in[0];
    const float* Wq = (const float*)d_in[1];
    const float* bq = (const float*)d_in[2];
    const float* Wk = (const float*)d_in[3];
    const float* bk = (const float*)d_in[4];
    const float* Wv = (const float*)d_in[5];
    const float* bv = (const float*)d_in[6];
    const float* Wp = (const float*)d_in[7];
    const float* bp = (const float*)d_in[8];
    wsa3d<<<2048, 256, 0, stream>>>(x, Wq, bq, Wk, bk, Wv, bv, Wp, bp, (float*)d_out);
}

// Round 6
// 68.723 us; speedup vs baseline: 2.6086x; 1.0882x over previous
//
#include <hip/hip_runtime.h>

typedef _Float16 f16;
typedef __attribute__((ext_vector_type(4))) _Float16 f16x4;
typedef __attribute__((ext_vector_type(8))) _Float16 f16x8;
typedef __attribute__((ext_vector_type(4))) float f32x4;

#define MFMA32(a,b,c) __builtin_amdgcn_mfma_f32_16x16x32_f16((a),(b),(c),0,0,0)
#define MFMA16(a,b,c) __builtin_amdgcn_mfma_f32_16x16x16f16((a),(b),(c),0,0,0)

// ---- pre-kernel: pack W{q,k,v,p} into per-lane f16 A-fragments in ws.
// frag c = m*8 + ob*2 + s  (m: 0=q 1=k 2=v 3=p); lane l holds row ob*16+(l&15),
// k = 8*(l>>4) + 32*s + [0,8). Stored at ws[c*512 + l*8] (f16 units) -> main-kernel
// loads are 16B/lane fully coalesced and L2-resident.
__global__ void wprep(const float* __restrict__ Wq, const float* __restrict__ Wk,
                      const float* __restrict__ Wv, const float* __restrict__ Wp,
                      f16* __restrict__ ws)
{
    const int t = threadIdx.x;
    const int lane = t & 63;
    const float* Wm[4] = {Wq, Wk, Wv, Wp};
    #pragma unroll
    for (int j = 0; j < 8; ++j) {
        const int c = (t >> 6) * 8 + j;
        const int m = c >> 3, ob = (c >> 1) & 3, s = c & 1;
        const float* src = Wm[m] + (ob * 16 + (lane & 15)) * 64 + 8 * (lane >> 4) + 32 * s;
        f32x4 a4 = *(const f32x4*)src;
        f32x4 b4 = *(const f32x4*)(src + 4);
        f16x8 h;
        #pragma unroll
        for (int ii = 0; ii < 8; ++ii) h[ii] = (f16)(ii < 4 ? a4[ii] : b4[ii - 4]);
        *(f16x8*)(ws + c * 512 + lane * 8) = h;
    }
}

// One block = 4 consecutive-iw windows; wave w owns window w end-to-end.
// LDS 50,240 B -> 3 blocks/CU:
//   XW [0,32KB):      per-window 8KB tile: xw[64t][64c] -> vv[64c][64t] -> o_t[64t][64c]
//                     (aliased; all post-B1 access is wave-private, addr(row,col) =
//                      row*64 + ((col>>3 ^ (row&7) ^ win)<<3) + (col&7))
//   SG [32KB,+17472): f32 out-staging, 4 win x 16 o x 68-stride
// P matrix lives entirely in registers: swapped-S^T D-layout == K16 PV B-frag layout.
// ONE barrier in the main body (B1); tail has the 4 staged-scatter rounds.
__global__ __launch_bounds__(256, 3)
void wsa3d(const float* __restrict__ x, const f16* __restrict__ wsf,
           const float* __restrict__ bq, const float* __restrict__ bk,
           const float* __restrict__ bv, const float* __restrict__ bp,
           float* __restrict__ out)
{
    __shared__ __align__(16) unsigned char smem[50240];
    f16*   const XW = (f16*)smem;
    float* const SG = (float*)(smem + 32768);

    const int tid  = threadIdx.x;
    const int lane = tid & 63;
    const int w    = tid >> 6;
    const int g    = lane >> 4;
    const int ln16 = lane & 15;
    const int key  = ln16 & 7;

    // XCD swizzle (2048 % 8 == 0 -> bijective): 256 consecutive quads per XCD
    const int bid = blockIdx.x;
    const int Q   = ((bid & 7) << 8) | (bid >> 3);
    const int qx = Q & 3, ih = (Q >> 2) & 15, idz = (Q >> 6) & 15, b = Q >> 10;

    const float c_sc = 0.25f * 1.44269504088896340736f;  // scale * log2(e)
    const f32x4 z4 = {0.f, 0.f, 0.f, 0.f};

    const int gz = (lane >> 4) & 3, gy = (lane >> 2) & 3, gq = lane & 3;

    // ---- gather (coalesced, 16 lines/inst): channel c = w*16+i, window gq
    f32x4 vals[16];
    #pragma unroll
    for (int i = 0; i < 16; ++i) {
        const int c = w * 16 + i;
        vals[i] = *(const f32x4*)(x + ((((b*64 + c)*64 + idz*4 + gz)*64) + ih*4 + gy)*64 + qx*16 + gq*4);
    }
    // ---- pack -> xw of window gq (cross-wave: wave w supplies channels [16w,16w+16))
    #pragma unroll
    for (int lx = 0; lx < 4; ++lx) {
        const int t = gz * 16 + gy * 4 + lx;
        #pragma unroll
        for (int h2 = 0; h2 < 2; ++h2) {
            f16x8 pk;
            #pragma unroll
            for (int ii = 0; ii < 8; ++ii) pk[ii] = (f16)vals[h2 * 8 + ii][lx];
            *(f16x8*)(XW + gq*4096 + t*64 + (((w*2 + h2) ^ (t & 7) ^ gq) << 3)) = pk;
        }
    }
    __syncthreads();   // B1: the only main-body barrier

    // ---- xw fragments (B for q/k proj, A for v^T proj)
    f16x8 xf[4][2];
    #pragma unroll
    for (int lb = 0; lb < 4; ++lb)
        #pragma unroll
        for (int s = 0; s < 2; ++s)
            xf[lb][s] = *(const f16x8*)(XW + w*4096 + (lb*16 + ln16)*64 + (((g + 4*s) ^ key ^ w) << 3));

    // ---- v^T projection -> vv[ch][tok] (overwrites xw of window w; same-wave safe)
    #pragma unroll
    for (int ob = 0; ob < 4; ++ob) {
        f16x8 VF[2];
        #pragma unroll
        for (int s = 0; s < 2; ++s) VF[s] = *(const f16x8*)(wsf + (16 + ob*2 + s)*512 + lane*8);
        const float bvo = bv[ob * 16 + ln16];
        #pragma unroll
        for (int tb = 0; tb < 4; ++tb) {
            f32x4 a = z4;
            #pragma unroll
            for (int s = 0; s < 2; ++s) a = MFMA32(xf[tb][s], VF[s], a);
            f16x4 h4;
            #pragma unroll
            for (int r = 0; r < 4; ++r) h4[r] = (f16)(a[r] + bvo);
            *(f16x4*)(XW + w*4096 + (ob*16 + ln16)*64 + (((2*tb + (g >> 1)) ^ key ^ w) << 3) + 4*(g & 1)) = h4;
        }
    }

    // ---- attention, head-sequential, P fully in registers
    f16x4 ot[4][4];
    #pragma unroll
    for (int h = 0; h < 4; ++h) {
        f16x8 QF[2], KF[2];
        #pragma unroll
        for (int s = 0; s < 2; ++s) {
            QF[s] = *(const f16x8*)(wsf + (h*2 + s)*512 + lane*8);
            KF[s] = *(const f16x8*)(wsf + (8 + h*2 + s)*512 + lane*8);
        }
        const f32x4 bqv = *(const f32x4*)(bq + h*16 + g*4);
        const f32x4 bkv = *(const f32x4*)(bk + h*16 + g*4);
        // q/k proj: C-layout == K16 frag layout (lane: d=4g+r, tok=16lb+ln16)
        f16x4 qf[4], kf[4];
        #pragma unroll
        for (int lb = 0; lb < 4; ++lb) {
            f32x4 aq = z4, ak = z4;
            #pragma unroll
            for (int s = 0; s < 2; ++s) {
                aq = MFMA32(QF[s], xf[lb][s], aq);
                ak = MFMA32(KF[s], xf[lb][s], ak);
            }
            #pragma unroll
            for (int r = 0; r < 4; ++r) {
                qf[lb][r] = (f16)((aq[r] + bqv[r]) * c_sc);
                kf[lb][r] = (f16)(ak[r] + bkv[r]);
            }
        }
        // v A-fragments for this head: row d = ln16 (ch 16h+ln16), k = j = 16jb+4g+ii
        f16x4 va[4];
        #pragma unroll
        for (int jb = 0; jb < 4; ++jb)
            va[jb] = *(const f16x4*)(XW + w*4096 + (16*h + ln16)*64 + (((2*jb + (g >> 1)) ^ key ^ w) << 3) + 4*(g & 1));
        // per ib: S^T (4 MFMA16) -> exp -> sum (in-lane + 2 shfl) -> PV (4 MFMA16, P from regs)
        #pragma unroll
        for (int ib = 0; ib < 4; ++ib) {
            f32x4 e[4];
            #pragma unroll
            for (int jb = 0; jb < 4; ++jb) {
                f32x4 S = MFMA16(kf[jb], qf[ib], z4);   // D: row=j (16jb+4g+r), col=i (16ib+ln16)
                #pragma unroll
                for (int r = 0; r < 4; ++r) e[jb][r] = __builtin_amdgcn_exp2f(S[r]);
            }
            f32x4 s4 = e[0] + e[1] + e[2] + e[3];
            float hh = (s4[0] + s4[1]) + (s4[2] + s4[3]);
            hh += __shfl_xor(hh, 16);
            hh += __shfl_xor(hh, 32);
            const float inv = __builtin_amdgcn_rcpf(hh);
            f32x4 O = z4;
            #pragma unroll
            for (int jb = 0; jb < 4; ++jb) {
                f16x4 pf;
                #pragma unroll
                for (int r = 0; r < 4; ++r) pf[r] = (f16)e[jb][r];
                O = MFMA16(va[jb], pf, O);              // D: row=d (4g+r), col=i (16ib+ln16)
            }
            #pragma unroll
            for (int r = 0; r < 4; ++r) ot[h][ib][r] = (f16)(O[r] * inv);
        }
    }

    // ---- o_t[tok][ch] stores (vv dead now; same-wave ordering)
    #pragma unroll
    for (int h = 0; h < 4; ++h)
        #pragma unroll
        for (int ib = 0; ib < 4; ++ib)
            *(f16x4*)(XW + w*4096 + (16*ib + ln16)*64 + (((2*h + (g >> 1)) ^ key ^ w) << 3) + 4*(g & 1)) = ot[h][ib];

    // ---- output projection: D2[t][o] = sum_c o_t[t][c] Wp[o][c]
    f16x8 PF[4][2];
    #pragma unroll
    for (int oc = 0; oc < 4; ++oc)
        #pragma unroll
        for (int s = 0; s < 2; ++s) PF[oc][s] = *(const f16x8*)(wsf + (24 + oc*2 + s)*512 + lane*8);
    float bps[4];
    #pragma unroll
    for (int oc = 0; oc < 4; ++oc) bps[oc] = bp[oc * 16 + ln16];

    f32x4 res[4][4];
    #pragma unroll
    for (int tb = 0; tb < 4; ++tb) {
        f16x8 af[2];
        #pragma unroll
        for (int s = 0; s < 2; ++s)
            af[s] = *(const f16x8*)(XW + w*4096 + (tb*16 + ln16)*64 + (((g + 4*s) ^ key ^ w) << 3));
        #pragma unroll
        for (int oc = 0; oc < 4; ++oc) {
            f32x4 a = z4;
            #pragma unroll
            for (int s = 0; s < 2; ++s) a = MFMA32(af[s], PF[oc][s], a);
            #pragma unroll
            for (int r = 0; r < 4; ++r) res[tb][oc][r] = a[r] + bps[oc];
        }
    }

    // ---- staged, coalesced scatter (4 oc rounds)
    #pragma unroll
    for (int oc = 0; oc < 4; ++oc) {
        #pragma unroll
        for (int tb = 0; tb < 4; ++tb)
            *(f32x4*)(SG + w*1092 + ln16*68 + ((tb*16 + g*4) ^ (w << 2))) = res[tb][oc];
        __syncthreads();
        #pragma unroll
        for (int si = 0; si < 4; ++si) {
            const int o2 = w * 4 + si;
            f32x4 v4 = *(const f32x4*)(SG + gq*1092 + o2*68 + ((gz*16 + gy*4) ^ (gq << 2)));
            *(f32x4*)(out + ((((b*64 + oc*16 + o2)*64 + idz*4 + gz)*64) + ih*4 + gy)*64 + qx*16 + gq*4) = v4;
        }
        if (oc < 3) __syncthreads();
    }
}

extern "C" void kernel_launch(void* const* d_in, const int* in_sizes, int n_in,
                              void* d_out, int out_size, void* d_ws, size_t ws_size,
                              hipStream_t stream) {
    (void)in_sizes; (void)n_in; (void)out_size; (void)ws_size;
    const float* x  = (const float*)d_in[0];
    const float* Wq = (const float*)d_in[1];
    const float* bq = (const float*)d_in[2];
    const float* Wk = (const float*)d_in[3];
    const float* bk = (const float*)d_in[4];
    const float* Wv = (const float*)d_in[5];
    const float* bv = (const float*)d_in[6];
    const float* Wp = (const float*)d_in[7];
    const float* bp = (const float*)d_in[8];
    f16* wsf = (f16*)d_ws;
    wprep<<<1, 256, 0, stream>>>(Wq, Wk, Wv, Wp, wsf);
    wsa3d<<<2048, 256, 0, stream>>>(x, wsf, bq, bk, bv, bp, (float*)d_out);
}